// Round 2
// baseline (315.210 us; speedup 1.0000x reference)
//
#include <hip/hip_runtime.h>
#include <stdint.h>

#define NF 8192
#define NX 2048
#define MROWS 8192
#define NGROUPS 32
#define NTILE 32   // NX/64 K-tiles

typedef unsigned short u16;
typedef __bf16 bf16x8 __attribute__((ext_vector_type(8)));
typedef float f32x16 __attribute__((ext_vector_type(16)));

#define AS1 __attribute__((address_space(1)))
#define AS3 __attribute__((address_space(3)))

// async global->LDS, 16B/lane; LDS dest = wave-uniform base + lane*16.
__device__ __forceinline__ void glds16(const void* g, void* l) {
    __builtin_amdgcn_global_load_lds((AS1 void*)(uintptr_t)g,
                                     (AS3 void*)(uintptr_t)l, 16, 0, 0);
}

__device__ __forceinline__ u16 f2bf(float f) {
    unsigned u = __float_as_uint(f);
    return (u16)((u + 0x7FFFu + ((u >> 16) & 1u)) >> 16);  // RNE
}

// packed [NF, NX/2] (one byte per int32, two nibbles) -> W bf16 [NF, NX] row-major.
__global__ void dequant_kernel(const int* __restrict__ packed,
                               const float* __restrict__ scales,
                               const int* __restrict__ zeros,
                               uint32_t* __restrict__ W2) {
    int tid = blockIdx.x * blockDim.x + threadIdx.x;   // [0, NF*NX/2)
    int f = tid >> 10;          // NX/2 = 1024 per row
    int i = tid & 1023;
    int g = f * NGROUPS + (i >> 5);
    int p = packed[tid];
    float s = scales[g];
    float z = (float)zeros[g];
    float w0 = ((float)(p & 15) - z) * s;
    float w1 = ((float)((p >> 4) & 15) - z) * s;
    W2[tid] = (uint32_t)f2bf(w0) | ((uint32_t)f2bf(w1) << 16);
}

// x fp32 -> bf16, 4 elems/thread
__global__ void cvt_kernel(const float4* __restrict__ x, ushort4* __restrict__ y) {
    int i = blockIdx.x * blockDim.x + threadIdx.x;
    float4 v = x[i];
    ushort4 o;
    o.x = f2bf(v.x); o.y = f2bf(v.y); o.z = f2bf(v.z); o.w = f2bf(v.w);
    y[i] = o;
}

// ===========================================================================
// 256x256 tile, BK=64, 8 waves (2Mx4N), mfma_f32_32x32x16_bf16, one K-step
// (K=16) per phase, 4 phases/tile, ONE barrier per phase. Register reads are
// pipelined one phase ahead (reads at phase p feed phase p+1's MFMA; entry
// lgkmcnt(0) is ~free). Stages are strict 1-tile-ahead into the INACTIVE
// buffer: {A1,A2,B2}@ph0, {B1}@ph1, vmcnt(0)@ph2-end (nothing else in
// flight), ph3 pre-reads kstep0(T+1) from the completed buffer.
//
// LDS per buffer (64 KiB), 2 buffers = 128 KiB:
//   +0      A1: region-row r: r<64 -> block-row r       ; r>=64 -> 128+(r-64)
//   +16384  A2: region-row r: r<64 -> block-row 64+r    ; r>=64 -> 192+(r-64)
//   +32768  B2: region-row r -> block-row (r>>5)*64 + (r&31)        (ntile 0)
//   +49152  B1: region-row r -> block-row (r>>5)*64 + 32 + (r&31)   (ntile 1)
// Row = 128 B (64 k bf16). T2 swizzle: 16B slot s at phys s^(row&7); write
// side keeps LDS linear and inverse-swizzles the GLOBAL source slot.
//
// Fragment layouts (32x32x16 bf16):
//   A: row = lane&31, k = (lane>>5)*8 + e   (8 contiguous k -> 1 ds_read_b128)
//   B: col = lane&31, k = (lane>>5)*8 + e   (B^T storage -> same addressing)
//   C/D: col = lane&31, row = (reg&3) + 8*(reg>>2) + 4*(lane>>5)  [m74/m101]
//
// Hazard summary (hand-checked):
//  - stage targets are always the inactive buffer; its last readers issued
//    >= 1 full phase before the stage's entry barrier (ds sample latency
//    ~120cy << phase ~600cy; glds LDS-write lands >= global latency later).
//  - ph3's cross-buffer reads follow vmcnt(0)+barrier at ph2-end.
//  - frag banks: ph0 uses A/B bank0, reads bank1; alternating; 4 phases/tile
//    keeps the parity tile-independent (all static register names).
// ===========================================================================

#define BAR    __builtin_amdgcn_s_barrier()
#define LGKM0  asm volatile("s_waitcnt lgkmcnt(0)" ::: "memory")
#define VMCNT0 asm volatile("s_waitcnt vmcnt(0)" ::: "memory")
#define FENCE  __builtin_amdgcn_sched_barrier(0)

#define STAGE(unitOff, bufOff, s0, s1, koff) do { \
    glds16((s0) + (koff), dst0 + (unitOff) + (bufOff)); \
    glds16((s1) + (koff), dst1 + (unitOff) + (bufOff)); \
} while (0)

#define LD8(off) (*(const bf16x8*)(smem + (off)))
#define SWZ(K) (((((K)*2) + hi) ^ l7) << 4)

#define RDA(arr, BUF, K) do { \
    arr[0] = LD8((BUF) + aRow +         SWZ(K)); \
    arr[1] = LD8((BUF) + aRow + 4096  + SWZ(K)); \
    arr[2] = LD8((BUF) + aRow + 16384 + SWZ(K)); \
    arr[3] = LD8((BUF) + aRow + 20480 + SWZ(K)); \
} while (0)

#define RDB(arr, BUF, K) do { \
    arr[0] = LD8((BUF) + bRow + 32768 + SWZ(K)); \
    arr[1] = LD8((BUF) + bRow + 49152 + SWZ(K)); \
} while (0)

#define MM(A_, B_) do { \
    _Pragma("unroll") \
    for (int i_ = 0; i_ < 4; ++i_) { \
        acc[i_][0] = __builtin_amdgcn_mfma_f32_32x32x16_bf16(A_[i_], B_[0], acc[i_][0], 0, 0, 0); \
        acc[i_][1] = __builtin_amdgcn_mfma_f32_32x32x16_bf16(A_[i_], B_[1], acc[i_][1], 0, 0, 0); \
    } \
} while (0)

__global__ __launch_bounds__(512, 2)
void gemm_kernel(const u16* __restrict__ A, const u16* __restrict__ B,
                 const float* __restrict__ bias, float* __restrict__ C) {
    __shared__ __align__(16) char smem[131072];

    const int t = threadIdx.x;

    // T1: bijective XCD swizzle (1024 blocks % 8 == 0).
    const int bid = blockIdx.x;
    const int swz = (bid & 7) * 128 + (bid >> 3);
    const int by = swz >> 5;
    const int bx = swz & 31;
    const int rowA0 = by * 256;
    const int rowB0 = bx * 256;

    // ---- staging addressing (inverse-swizzled global source) ----
    const int tr = t >> 3;                 // lds-row within unit for load 0
    const int slot = (t & 7) ^ (tr & 7);   // source 16B-slot (involution)
    const int s16 = slot * 16;

    const char* Ab = (const char*)A;       // row stride NX*2 = 4096 B
    const char* Bb = (const char*)B;
    const char* srcA1_0 = Ab + (size_t)(rowA0 + tr)       * 4096 + s16;
    const char* srcA1_1 = Ab + (size_t)(rowA0 + 128 + tr) * 4096 + s16;
    const char* srcA2_0 = Ab + (size_t)(rowA0 + 64 + tr)  * 4096 + s16;
    const char* srcA2_1 = Ab + (size_t)(rowA0 + 192 + tr) * 4096 + s16;
    const int rb = (tr >> 5) * 64 + (tr & 31);
    const char* srcB2_0 = Bb + (size_t)(rowB0 + rb)       * 4096 + s16;
    const char* srcB2_1 = Bb + (size_t)(rowB0 + 128 + rb) * 4096 + s16;
    const char* srcB1_0 = Bb + (size_t)(rowB0 + 32 + rb)  * 4096 + s16;
    const char* srcB1_1 = Bb + (size_t)(rowB0 + 160 + rb) * 4096 + s16;

    char* dst0 = smem + t * 16;            // linear LDS dest (glds requirement)
    char* dst1 = smem + (t + 512) * 16;

    // ---- fragment read addressing (swizzled) ----
    const int lane = t & 63;
    const int wv = t >> 6;
    const int wm = wv >> 2;                // 0..1  (M half, 128 rows)
    const int wn = wv & 3;                 // 0..3  (N quarter, 64 cols)
    const int l31 = lane & 31;
    const int hi = lane >> 5;              // k-group (0/1)
    const int l7 = lane & 7;
    const int aRow = (wm * 64 + l31) * 128;   // A region-row byte offset
    const int bRow = (wn * 32 + l31) * 128;   // B region-row byte offset

    f32x16 acc[4][2];
#pragma unroll
    for (int i = 0; i < 4; ++i)
#pragma unroll
        for (int n = 0; n < 2; ++n)
#pragma unroll
            for (int r = 0; r < 16; ++r) acc[i][n][r] = 0.f;

    bf16x8 aA[4], aB[4], bA[2], bB[2];

    // ---- prologue: stage tile0 into buf0, drain, read kstep0 -> bank A ----
    STAGE(0,     0, srcA1_0, srcA1_1, 0);
    STAGE(16384, 0, srcA2_0, srcA2_1, 0);
    STAGE(32768, 0, srcB2_0, srcB2_1, 0);
    STAGE(49152, 0, srcB1_0, srcB1_1, 0);
    VMCNT0;
    BAR;
    RDA(aA, 0, 0);
    RDB(bA, 0, 0);

    int kNext = 128;   // byte K-offset of tile T+1

#pragma unroll 1
    for (int T = 0; T < NTILE; ++T) {
        const int bo = (T & 1) << 16;   // active buffer
        const int so = bo ^ 65536;      // inactive buffer (receives T+1)
        const bool more = (T + 1 < NTILE);

        // ---------- phase 0: MFMA k0 (bankA); reads k1 -> bankB; stage A1,A2,B2(T+1) ----------
        FENCE; BAR; LGKM0; FENCE;
        RDA(aB, bo, 1);
        RDB(bB, bo, 1);
        if (more) {
            STAGE(0,     so, srcA1_0, srcA1_1, kNext);
            STAGE(16384, so, srcA2_0, srcA2_1, kNext);
            STAGE(32768, so, srcB2_0, srcB2_1, kNext);
        }
        __builtin_amdgcn_s_setprio(1);
        MM(aA, bA);
        __builtin_amdgcn_s_setprio(0);

        // ---------- phase 1: MFMA k1 (bankB); reads k2 -> bankA; stage B1(T+1) ----------
        FENCE; BAR; LGKM0; FENCE;
        RDA(aA, bo, 2);
        RDB(bA, bo, 2);
        if (more) STAGE(49152, so, srcB1_0, srcB1_1, kNext);
        __builtin_amdgcn_s_setprio(1);
        MM(aB, bB);
        __builtin_amdgcn_s_setprio(0);

        // ---------- phase 2: MFMA k2 (bankA); reads k3 -> bankB; drain stages ----------
        FENCE; BAR; LGKM0; FENCE;
        RDA(aB, bo, 3);
        RDB(bB, bo, 3);
        __builtin_amdgcn_s_setprio(1);
        MM(aA, bA);
        __builtin_amdgcn_s_setprio(0);
        FENCE;
        VMCNT0;   // T+1's 4 units are the only outstanding loads

        // ---------- phase 3: MFMA k3 (bankB); pre-read kstep0(T+1) -> bankA ----------
        FENCE; BAR; LGKM0; FENCE;
        if (more) {
            RDA(aA, so, 0);
            RDB(bA, so, 0);
        }
        __builtin_amdgcn_s_setprio(1);
        MM(aB, bB);
        __builtin_amdgcn_s_setprio(0);

        kNext += 128;
    }

    // ---- epilogue: C/D col = l31, row = (r&3) + 8*(r>>2) + 4*hi ----
    const int col0 = rowB0 + wn * 64 + l31;
    const int row0 = rowA0 + wm * 128 + 4 * hi;
    const float bj0 = bias[col0];
    const float bj1 = bias[col0 + 32];
    float* Cbase = C + col0;
#pragma unroll
    for (int i = 0; i < 4; ++i) {
#pragma unroll
        for (int r = 0; r < 16; ++r) {
            const int row = row0 + i * 32 + (r & 3) + 8 * (r >> 2);
            float* crow = Cbase + (size_t)row * NF;
            __builtin_nontemporal_store(acc[i][0][r] + bj0, crow);
            __builtin_nontemporal_store(acc[i][1][r] + bj1, crow + 32);
        }
    }
}

extern "C" void kernel_launch(void* const* d_in, const int* in_sizes, int n_in,
                              void* d_out, int out_size, void* d_ws, size_t ws_size,
                              hipStream_t stream) {
    const float* x      = (const float*)d_in[0];   // [4,2048,2048] fp32
    const int* packed   = (const int*)d_in[1];     // [8192,1024]
    const float* scales = (const float*)d_in[2];   // [8192,32]
    const int* zeros    = (const int*)d_in[3];     // [8192,32]
    const float* bias   = (const float*)d_in[4];   // [8192]
    float* out = (float*)d_out;                    // [8192, 8192] fp32

    // workspace: W bf16 (32 MiB) + x bf16 (32 MiB); fully rewritten every call
    u16* Wq = (u16*)d_ws;
    u16* Xb = Wq + (size_t)NF * NX;

    dequant_kernel<<<(NF * (NX / 2)) / 256, 256, 0, stream>>>(packed, scales, zeros, (uint32_t*)Wq);
    cvt_kernel<<<(MROWS * NX / 4) / 256, 256, 0, stream>>>((const float4*)x, (ushort4*)Xb);

    gemm_kernel<<<dim3((MROWS / 256) * (NF / 256)), 512, 0, stream>>>(Xb, Wq, bias, out);
}